// Round 5
// baseline (463.045 us; speedup 1.0000x reference)
//
#include <hip/hip_runtime.h>

#define NN 50000
#define NE 800000
#define D 128
#define NEG 0.2f

#define NBLK1 256        // pass-1 blocks
#define TILE1 3125       // NE / NBLK1 (exact)
#define NB2 196          // coarse buckets (dst>>8)
#define CAP2 8192        // max edges per coarse bucket
#define NTB 391          // ceil(NN/128) node tiles

typedef short bf8_t __attribute__((ext_vector_type(8)));   // 8 x bf16 (16 B)
typedef float f4_t __attribute__((ext_vector_type(4)));

__device__ __forceinline__ unsigned short f2bf(float f) {
  unsigned int u = __float_as_uint(f);
  return (unsigned short)((u + 0x7FFF + ((u >> 16) & 1)) >> 16);  // RNE
}
__device__ __forceinline__ float bf2f(unsigned int b) { return __uint_as_float(b << 16); }

// XOR-swizzled short-index of a 16B chunk start (row stride = 128 shorts).
// chunk' = chunk ^ (row & 7) -> A/B-frag reads land 2 lanes/bank (free).
__device__ __forceinline__ int swz(int row, int chunk) {
  return row * D + ((chunk ^ (row & 7)) << 3);
}

__device__ __forceinline__ f4_t MF(bf8_t a, bf8_t b, f4_t c) {
  return __builtin_amdgcn_mfma_f32_16x16x32_bf16(a, b, c, 0, 0, 0);
}

// ---------------- shared GEMM helpers ----------------

__device__ __forceinline__ void stage_w(unsigned short* wbuf,
                                        const unsigned short* __restrict__ WT, int t) {
#pragma unroll
  for (int i = 0; i < 8; ++i) {
    int idx8 = t + i * 256;          // 2048 16B chunks
    int n = idx8 >> 4, c = idx8 & 15;
    *(uint4*)(wbuf + swz(n, c)) = *(const uint4*)(WT + n * D + c * 8);
  }
}

__device__ __forceinline__ void zero_acc(f4_t (&acc)[2][8]) {
#pragma unroll
  for (int rt = 0; rt < 2; ++rt)
#pragma unroll
    for (int nt = 0; nt < 8; ++nt) acc[rt][nt] = (f4_t){0.f, 0.f, 0.f, 0.f};
}

__device__ __forceinline__ void compute_tile(const unsigned short* wbuf,
                                             const bf8_t (&afr)[2][4],
                                             int l15, int quad, f4_t (&acc)[2][8]) {
#pragma unroll
  for (int kc = 0; kc < 4; ++kc) {
#pragma unroll
    for (int nt = 0; nt < 8; ++nt) {
      int n = nt * 16 + l15;
      bf8_t b = *(const bf8_t*)(wbuf + swz(n, kc * 4 + quad));
      acc[0][nt] = MF(afr[0][kc], b, acc[0][nt]);
      acc[1][nt] = MF(afr[1][kc], b, acc[1][nt]);
    }
  }
}

__device__ __forceinline__ void load_afr_lds(const unsigned short* hbuf, int wave,
                                             int l15, int quad, bf8_t (&afr)[2][4]) {
#pragma unroll
  for (int rt = 0; rt < 2; ++rt) {
    int r = wave * 32 + rt * 16 + l15;
#pragma unroll
    for (int kc = 0; kc < 4; ++kc)
      afr[rt][kc] = *(const bf8_t*)(hbuf + swz(r, kc * 4 + quad));
  }
}

__device__ __forceinline__ void load_afr_g(const unsigned short* __restrict__ A, int base,
                                           int wave, int l15, int quad, bf8_t (&afr)[2][4]) {
#pragma unroll
  for (int rt = 0; rt < 2; ++rt) {
    int r = base + wave * 32 + rt * 16 + l15;
    if (r >= NN) r = NN - 1;
    const unsigned short* p = A + (size_t)r * D + quad * 8;
#pragma unroll
    for (int kc = 0; kc < 4; ++kc) afr[rt][kc] = *(const bf8_t*)(p + kc * 32);
  }
}

__device__ __forceinline__ void load_afr_f32(const float* __restrict__ A, int base,
                                             int wave, int l15, int quad, bf8_t (&afr)[2][4]) {
#pragma unroll
  for (int rt = 0; rt < 2; ++rt) {
    int r = base + wave * 32 + rt * 16 + l15;
    if (r >= NN) r = NN - 1;
    const float* p = A + (size_t)r * D + quad * 8;
#pragma unroll
    for (int kc = 0; kc < 4; ++kc) {
      float4 u = *(const float4*)(p + kc * 32);
      float4 v = *(const float4*)(p + kc * 32 + 4);
      bf8_t f;
      f[0] = (short)f2bf(u.x); f[1] = (short)f2bf(u.y);
      f[2] = (short)f2bf(u.z); f[3] = (short)f2bf(u.w);
      f[4] = (short)f2bf(v.x); f[5] = (short)f2bf(v.y);
      f[6] = (short)f2bf(v.z); f[7] = (short)f2bf(v.w);
      afr[rt][kc] = f;
    }
  }
}

__device__ __forceinline__ void store_bf(const f4_t (&acc)[2][8],
                                         const float* __restrict__ bias,
                                         unsigned short* __restrict__ C,
                                         int base, int wave, int l15, int quad) {
#pragma unroll
  for (int rt = 0; rt < 2; ++rt)
#pragma unroll
    for (int nt = 0; nt < 8; ++nt) {
      int col = nt * 16 + l15;
      float b = bias[col];
#pragma unroll
      for (int reg = 0; reg < 4; ++reg) {
        int row = base + wave * 32 + rt * 16 + quad * 4 + reg;
        if (row < NN) C[(size_t)row * D + col] = f2bf(acc[rt][nt][reg] + b);
      }
    }
}

// aggregate 128 nodes of this tile into hbuf (bf16, swizzled layout)
__device__ __forceinline__ void agg_tile(unsigned short* hbuf,
                                         const int* __restrict__ rowptr,
                                         const int* __restrict__ ssrc,
                                         const int* __restrict__ deg,
                                         const unsigned short* __restrict__ hqin,
                                         const unsigned short* __restrict__ hkin,
                                         int base, int wave, int lane) {
  for (int i = wave; i < 128; i += 4) {
    int v = base + i;
    if (v >= NN) break;
    int beg = rowptr[v], end = rowptr[v + 1];
    unsigned int qb = *(const unsigned int*)(hqin + (size_t)v * D + lane * 2);
    float q0 = bf2f(qb & 0xFFFFu), q1 = bf2f(qb >> 16);
    float a0 = 0.f, a1 = 0.f;
    int e = beg;
    for (; e + 8 <= end; e += 8) {
      unsigned int kk[8];
#pragma unroll
      for (int j = 0; j < 8; ++j)
        kk[j] = *(const unsigned int*)(hkin + (size_t)ssrc[e + j] * D + lane * 2);
#pragma unroll
      for (int j = 0; j < 8; ++j) {
        float m0 = q0 + bf2f(kk[j] & 0xFFFFu); a0 += m0 >= 0.f ? m0 : NEG * m0;
        float m1 = q1 + bf2f(kk[j] >> 16);     a1 += m1 >= 0.f ? m1 : NEG * m1;
      }
    }
    for (; e < end; ++e) {
      unsigned int kb = *(const unsigned int*)(hkin + (size_t)ssrc[e] * D + lane * 2);
      float m0 = q0 + bf2f(kb & 0xFFFFu); a0 += m0 >= 0.f ? m0 : NEG * m0;
      float m1 = q1 + bf2f(kb >> 16);     a1 += m1 >= 0.f ? m1 : NEG * m1;
    }
    float dn = fmaxf((float)deg[v], 1.f);
    unsigned int ob = (unsigned int)f2bf(a0 / dn) | ((unsigned int)f2bf(a1 / dn) << 16);
    *(unsigned int*)(hbuf + swz(i, lane >> 2) + ((2 * lane) & 7)) = ob;
  }
}

// ---------------- weight prep: fp32 W[k][n] -> bf16 WT[n][k], 9 matrices ----------------
__global__ __launch_bounds__(256) void prep_weights(
    const float* __restrict__ Wq, const float* __restrict__ Wk,
    const float* __restrict__ Wr, const float* __restrict__ Wro,
    unsigned short* __restrict__ WT) {
  const int m = blockIdx.y;
  const float* src;
  if (m < 2) src = Wq + m * D * D;
  else if (m < 4) src = Wk + (m - 2) * D * D;
  else if (m < 6) src = Wr + (m - 4) * D * D;
  else src = Wro + (m - 6) * D * D;
  unsigned short* dstp = WT + m * D * D;
  const int t = threadIdx.x;
  const int n = blockIdx.x * 2 + (t >> 7);
  const int k = t & 127;
  dstp[n * D + k] = f2bf(src[k * D + n]);
}

// ---------------- CSR build: MSD counting sort, zero global atomics ----------------
__global__ __launch_bounds__(256) void p1_hist(const int* __restrict__ dst,
                                               int* __restrict__ H) {
  __shared__ int cnt[NB2];
  const int t = threadIdx.x;
  const int blk = blockIdx.x;
  if (t < NB2) cnt[t] = 0;
  __syncthreads();
  const int beg = blk * TILE1, end = beg + TILE1;
  for (int i = beg + t; i < end; i += 256) atomicAdd(&cnt[dst[i] >> 8], 1);
  __syncthreads();
  if (t < NB2) H[t * NBLK1 + blk] = cnt[t];
}

__global__ __launch_bounds__(256) void p1_scanA(const int* __restrict__ H,
                                                int* __restrict__ binbase) {
  __shared__ int bs[NB2];
  __shared__ int sd[256];
  const int t = threadIdx.x;
  const int wave = t >> 6, lane = t & 63;
  for (int bin = wave; bin < NB2; bin += 4) {
    const int* row = H + bin * NBLK1;
    int v = row[lane] + row[lane + 64] + row[lane + 128] + row[lane + 192];
    for (int off = 32; off; off >>= 1) v += __shfl_down(v, off, 64);
    if (lane == 0) bs[bin] = v;
  }
  __syncthreads();
  int x = (t < NB2) ? bs[t] : 0;
  sd[t] = x;
  __syncthreads();
  int acc = x;
  for (int off = 1; off < 256; off <<= 1) {
    int y = (t >= off) ? sd[t - off] : 0;
    __syncthreads();
    acc += y;
    sd[t] = acc;
    __syncthreads();
  }
  if (t < NB2) binbase[t] = acc - x;
  if (t == 0) binbase[NB2] = NE;
}

__global__ __launch_bounds__(256) void p1_scanC(const int* __restrict__ H,
                                                const int* __restrict__ binbase,
                                                int* __restrict__ gofs) {
  __shared__ int sd[256];
  const int bin = blockIdx.x;
  const int t = threadIdx.x;
  int x = H[bin * NBLK1 + t];
  sd[t] = x;
  __syncthreads();
  int acc = x;
  for (int off = 1; off < 256; off <<= 1) {
    int y = (t >= off) ? sd[t - off] : 0;
    __syncthreads();
    acc += y;
    sd[t] = acc;
    __syncthreads();
  }
  gofs[bin * NBLK1 + t] = binbase[bin] + (acc - x);
}

__global__ __launch_bounds__(256) void p1_scatter(const int* __restrict__ src,
                                                  const int* __restrict__ dst,
                                                  const int* __restrict__ gofs,
                                                  unsigned int* __restrict__ ebuf) {
  __shared__ int lofs[NB2];
  const int t = threadIdx.x;
  const int blk = blockIdx.x;
  if (t < NB2) lofs[t] = gofs[t * NBLK1 + blk];
  __syncthreads();
  const int beg = blk * TILE1, end = beg + TILE1;
  for (int i = beg + t; i < end; i += 256) {
    unsigned int d = (unsigned int)dst[i];
    int pos = atomicAdd(&lofs[d >> 8], 1);
    ebuf[pos] = (unsigned int)src[i] | (d << 16);
  }
}

__global__ __launch_bounds__(256) void p2_sort(const int* __restrict__ binbase,
                                               const unsigned int* __restrict__ ebuf,
                                               int* __restrict__ ssrc,
                                               int* __restrict__ rowptr,
                                               int* __restrict__ deg) {
  __shared__ int cnt[256], fill[256], sd[256];
  __shared__ unsigned int sorted[CAP2];
  const int b = blockIdx.x;
  const int t = threadIdx.x;
  const int beg = binbase[b], end = binbase[b + 1];
  const int n = end - beg;
  cnt[t] = 0;
  __syncthreads();
  for (int i = beg + t; i < end; i += 256)
    atomicAdd(&cnt[(ebuf[i] >> 16) & 255], 1);
  __syncthreads();
  int x = cnt[t];
  sd[t] = x;
  __syncthreads();
  int acc = x;
  for (int off = 1; off < 256; off <<= 1) {
    int y = (t >= off) ? sd[t - off] : 0;
    __syncthreads();
    acc += y;
    sd[t] = acc;
    __syncthreads();
  }
  const int excl = acc - x;
  fill[t] = excl;
  __syncthreads();
  for (int i = beg + t; i < end; i += 256) {
    unsigned int p = ebuf[i];
    int pos = atomicAdd(&fill[(p >> 16) & 255], 1);
    if (pos < CAP2) sorted[pos] = p;
  }
  __syncthreads();
  for (int i = t; i < n; i += 256) ssrc[beg + i] = (int)(sorted[i] & 0xFFFFu);
  const int node = (b << 8) + t;
  if (node < NN) {
    rowptr[node] = beg + excl;
    deg[node] = x;
  }
  if (b == 0 && t == 0) rowptr[NN] = NE;
}

// ---------------- K1: y-split single-phase GEMM: feats -> hq0 / hk0 ----------------
__global__ __launch_bounds__(256) void gemm_qk(const float* __restrict__ feats,
                                               const unsigned short* __restrict__ WT,
                                               const float* __restrict__ bq_,
                                               const float* __restrict__ bk_,
                                               unsigned short* __restrict__ hq,
                                               unsigned short* __restrict__ hk) {
  __shared__ unsigned short wbuf[D * D];
  const int t = threadIdx.x, wave = t >> 6, lane = t & 63;
  const int l15 = lane & 15, quad = lane >> 4;
  const int base = blockIdx.y * 128;
  const int sel = blockIdx.x;  // 0 -> Wq0/hq, 1 -> Wk0/hk (block-uniform)
  stage_w(wbuf, WT + (sel ? 2 * D * D : 0), t);
  bf8_t afr[2][4];
  load_afr_f32(feats, base, wave, l15, quad, afr);
  __syncthreads();
  f4_t acc[2][8];
  zero_acc(acc);
  compute_tile(wbuf, afr, l15, quad, acc);
  store_bf(acc, sel ? bk_ : bq_, sel ? hk : hq, base, wave, l15, quad);
}

// ---------------- K2: agg(layer0) -> h1 -> hq1, hk1; h1 also to global ----------------
__global__ __launch_bounds__(256) void mega_mid(
    const int* __restrict__ rowptr, const int* __restrict__ ssrc,
    const int* __restrict__ deg,
    const unsigned short* __restrict__ hqin, const unsigned short* __restrict__ hkin,
    const unsigned short* __restrict__ WTr, const float* __restrict__ br_,
    const unsigned short* __restrict__ WTq, const float* __restrict__ bq_,
    const unsigned short* __restrict__ WTk, const float* __restrict__ bk_,
    unsigned short* __restrict__ hqout, unsigned short* __restrict__ hkout,
    unsigned short* __restrict__ hout) {
  __shared__ unsigned short wbuf[D * D];
  __shared__ unsigned short hbuf[D * D];
  const int t = threadIdx.x, wave = t >> 6, lane = t & 63;
  const int l15 = lane & 15, quad = lane >> 4;
  const int base = blockIdx.x * 128;

  // P0: stage Wr + aggregate into hbuf
  stage_w(wbuf, WTr, t);
  agg_tile(hbuf, rowptr, ssrc, deg, hqin, hkin, base, wave, lane);
  __syncthreads();

  // P1: ag @ Wr
  bf8_t afr[2][4];
  load_afr_lds(hbuf, wave, l15, quad, afr);
  f4_t acc[2][8];
  zero_acc(acc);
  compute_tile(wbuf, afr, l15, quad, acc);
  __syncthreads();  // wbuf+hbuf reads done

  // P2: h1 = leaky(acc+br) -> hbuf (swizzled) + global; stage Wq
#pragma unroll
  for (int rt = 0; rt < 2; ++rt)
#pragma unroll
    for (int nt = 0; nt < 8; ++nt) {
      int col = nt * 16 + l15;
      float b = br_[col];
#pragma unroll
      for (int reg = 0; reg < 4; ++reg) {
        int r = wave * 32 + rt * 16 + quad * 4 + reg;
        float v = acc[rt][nt][reg] + b;
        v = v >= 0.f ? v : NEG * v;
        unsigned short s = f2bf(v);
        hbuf[swz(r, col >> 3) + (col & 7)] = s;
        int row = base + r;
        if (row < NN) hout[(size_t)row * D + col] = s;
      }
    }
  stage_w(wbuf, WTq, t);
  __syncthreads();

  // P3: h1 @ Wq -> hq1
  load_afr_lds(hbuf, wave, l15, quad, afr);
  zero_acc(acc);
  compute_tile(wbuf, afr, l15, quad, acc);
  store_bf(acc, bq_, hqout, base, wave, l15, quad);
  __syncthreads();  // wbuf reads done

  // P4/P5: h1 @ Wk -> hk1 (A-frags reused from regs)
  stage_w(wbuf, WTk, t);
  __syncthreads();
  zero_acc(acc);
  compute_tile(wbuf, afr, l15, quad, acc);
  store_bf(acc, bk_, hkout, base, wave, l15, quad);
}

// ---------------- K3: agg(layer1) -> h2; out = h2@Wro2 + h1@Wro1 + x0@Wro0 + biases ----
__global__ __launch_bounds__(256) void mega_last(
    const int* __restrict__ rowptr, const int* __restrict__ ssrc,
    const int* __restrict__ deg,
    const unsigned short* __restrict__ hqin, const unsigned short* __restrict__ hkin,
    const unsigned short* __restrict__ WTr, const float* __restrict__ br_,
    const unsigned short* __restrict__ WTro2, const unsigned short* __restrict__ WTro1,
    const unsigned short* __restrict__ WTro0,
    const unsigned short* __restrict__ h1, const float* __restrict__ feats,
    const float* __restrict__ bro_, float* __restrict__ out) {
  __shared__ unsigned short wbuf[D * D];
  __shared__ unsigned short hbuf[D * D];
  const int t = threadIdx.x, wave = t >> 6, lane = t & 63;
  const int l15 = lane & 15, quad = lane >> 4;
  const int base = blockIdx.x * 128;

  // P0: stage Wr1 + aggregate into hbuf
  stage_w(wbuf, WTr, t);
  agg_tile(hbuf, rowptr, ssrc, deg, hqin, hkin, base, wave, lane);
  __syncthreads();

  // P1: ag @ Wr1 -> h2 (regs)
  bf8_t afr[2][4];
  load_afr_lds(hbuf, wave, l15, quad, afr);
  f4_t acc[2][8];
  zero_acc(acc);
  compute_tile(wbuf, afr, l15, quad, acc);
  __syncthreads();

  // P2: h2 -> hbuf; stage Wro2
#pragma unroll
  for (int rt = 0; rt < 2; ++rt)
#pragma unroll
    for (int nt = 0; nt < 8; ++nt) {
      int col = nt * 16 + l15;
      float b = br_[col];
#pragma unroll
      for (int reg = 0; reg < 4; ++reg) {
        int r = wave * 32 + rt * 16 + quad * 4 + reg;
        float v = acc[rt][nt][reg] + b;
        v = v >= 0.f ? v : NEG * v;
        hbuf[swz(r, col >> 3) + (col & 7)] = f2bf(v);
      }
    }
  stage_w(wbuf, WTro2, t);
  __syncthreads();

  // P3: acc = h2 @ Wro2
  load_afr_lds(hbuf, wave, l15, quad, afr);
  zero_acc(acc);
  compute_tile(wbuf, afr, l15, quad, acc);
  __syncthreads();

  // P4/P5: acc += h1 @ Wro1   (A-frags from global h1)
  stage_w(wbuf, WTro1, t);
  load_afr_g(h1, base, wave, l15, quad, afr);
  __syncthreads();
  compute_tile(wbuf, afr, l15, quad, acc);
  __syncthreads();

  // P6/P7: acc += x0 @ Wro0   (A-frags from fp32 feats)
  stage_w(wbuf, WTro0, t);
  load_afr_f32(feats, base, wave, l15, quad, afr);
  __syncthreads();
  compute_tile(wbuf, afr, l15, quad, acc);

  // epilogue: single fp32 write, summed biases
#pragma unroll
  for (int rt = 0; rt < 2; ++rt)
#pragma unroll
    for (int nt = 0; nt < 8; ++nt) {
      int col = nt * 16 + l15;
      float b = bro_[col] + bro_[D + col] + bro_[2 * D + col];
#pragma unroll
      for (int reg = 0; reg < 4; ++reg) {
        int row = base + wave * 32 + rt * 16 + quad * 4 + reg;
        if (row < NN) out[(size_t)row * D + col] = acc[rt][nt][reg] + b;
      }
    }
}

// ---------------- launch ----------------
extern "C" void kernel_launch(void* const* d_in, const int* in_sizes, int n_in,
                              void* d_out, int out_size, void* d_ws, size_t ws_size,
                              hipStream_t stream) {
  const float* feats = (const float*)d_in[0];
  const float* Wq = (const float*)d_in[1];
  const float* bq = (const float*)d_in[2];
  const float* Wk = (const float*)d_in[3];
  const float* bk = (const float*)d_in[4];
  const float* Wr = (const float*)d_in[5];
  const float* br = (const float*)d_in[6];
  const float* Wro = (const float*)d_in[7];
  const float* bro = (const float*)d_in[8];
  const int* src = (const int*)d_in[9];
  const int* dst = (const int*)d_in[10];
  float* out = (float*)d_out;

  size_t off = 0;
  char* base = (char*)d_ws;
  auto alloc = [&](size_t bytes) -> void* {
    void* p = base + off;
    off += (bytes + 255) & ~(size_t)255;
    return p;
  };
  int* H = (int*)alloc((size_t)NB2 * NBLK1 * 4);
  int* gofs = (int*)alloc((size_t)NB2 * NBLK1 * 4);
  int* binbase = (int*)alloc((size_t)(NB2 + 1) * 4);
  unsigned int* ebuf = (unsigned int*)alloc((size_t)NE * 4);
  int* ssrc = (int*)alloc((size_t)NE * 4);
  int* rowptr = (int*)alloc((size_t)(NN + 1) * 4);
  int* deg = (int*)alloc((size_t)NN * 4);
  unsigned short* WT = (unsigned short*)alloc((size_t)9 * D * D * 2);
  unsigned short* hqA = (unsigned short*)alloc((size_t)NN * D * 2);
  unsigned short* hkA = (unsigned short*)alloc((size_t)NN * D * 2);
  unsigned short* hqB = (unsigned short*)alloc((size_t)NN * D * 2);
  unsigned short* hkB = (unsigned short*)alloc((size_t)NN * D * 2);
  unsigned short* h1 = (unsigned short*)alloc((size_t)NN * D * 2);

  prep_weights<<<dim3(64, 9), 256, 0, stream>>>(Wq, Wk, Wr, Wro, WT);

  p1_hist<<<NBLK1, 256, 0, stream>>>(dst, H);
  p1_scanA<<<1, 256, 0, stream>>>(H, binbase);
  p1_scanC<<<NB2, 256, 0, stream>>>(H, binbase, gofs);
  p1_scatter<<<NBLK1, 256, 0, stream>>>(src, dst, gofs, ebuf);
  p2_sort<<<NB2, 256, 0, stream>>>(binbase, ebuf, ssrc, rowptr, deg);

  const size_t WM = (size_t)D * D;

  // K1: feats -> hq0, hk0 (Wq0 at WT+0, Wk0 at WT+2*WM selected in-kernel)
  gemm_qk<<<dim3(2, NTB), 256, 0, stream>>>(feats, WT, bq, bk, hqA, hkA);

  // K2: layer-0 aggregate + Wr0 + leaky -> h1; h1 @ {Wq1, Wk1} -> hq1, hk1
  mega_mid<<<NTB, 256, 0, stream>>>(rowptr, ssrc, deg, hqA, hkA,
                                    WT + 4 * WM, br,
                                    WT + 1 * WM, bq + D,
                                    WT + 3 * WM, bk + D,
                                    hqB, hkB, h1);

  // K3: layer-1 aggregate + Wr1 + leaky -> h2; out = h2@Wro2 + h1@Wro1 + x0@Wro0 + b
  mega_last<<<NTB, 256, 0, stream>>>(rowptr, ssrc, deg, hqB, hkB,
                                     WT + 5 * WM, br + D,
                                     WT + 8 * WM, WT + 7 * WM, WT + 6 * WM,
                                     h1, feats, bro, out);
}

// Round 6
// 324.441 us; speedup vs baseline: 1.4272x; 1.4272x over previous
//
#include <hip/hip_runtime.h>

#define NN 50000
#define NE 800000
#define D 128
#define NEG 0.2f

#define NBLK1 256        // pass-1 blocks
#define TILE1 3125       // NE / NBLK1 (exact)
#define NB2 196          // coarse buckets (dst>>8)
#define CAP2 8192        // max edges per coarse bucket
#define NT64 782         // ceil(NN/64) row tiles

typedef short bf8_t __attribute__((ext_vector_type(8)));   // 8 x bf16 (16 B)
typedef float f4_t __attribute__((ext_vector_type(4)));

__device__ __forceinline__ unsigned short f2bf(float f) {
  unsigned int u = __float_as_uint(f);
  return (unsigned short)((u + 0x7FFF + ((u >> 16) & 1)) >> 16);  // RNE
}
__device__ __forceinline__ float bf2f(unsigned int b) { return __uint_as_float(b << 16); }

__device__ __forceinline__ f4_t MF(bf8_t a, bf8_t b, f4_t c) {
  return __builtin_amdgcn_mfma_f32_16x16x32_bf16(a, b, c, 0, 0, 0);
}

// ---------------- GEMM building blocks (64-row tile, 4 waves, 16 rows/wave) ----------

// W row-major [n][k] bf16, contiguous 32 KB copy (conflict-free stage).
__device__ __forceinline__ void stage_w(unsigned short* wbuf,
                                        const unsigned short* __restrict__ WT, int t) {
#pragma unroll
  for (int i = 0; i < 8; ++i) {
    int idx8 = t + i * 256;   // 2048 x 16B chunks
    *(uint4*)(wbuf + idx8 * 8) = *(const uint4*)(WT + idx8 * 8);
  }
}

__device__ __forceinline__ void load_a16(const unsigned short* __restrict__ A,
                                         int base, int l15, int quad, bf8_t (&afr)[4]) {
  int r = base + l15;
  if (r >= NN) r = NN - 1;
  const unsigned short* p = A + (size_t)r * D + quad * 8;
#pragma unroll
  for (int kc = 0; kc < 4; ++kc) afr[kc] = *(const bf8_t*)(p + kc * 32);
}

__device__ __forceinline__ void tile16(const unsigned short* wbuf, const bf8_t (&afr)[4],
                                       int l15, int quad, f4_t (&acc)[8]) {
#pragma unroll
  for (int kc = 0; kc < 4; ++kc)
#pragma unroll
    for (int nt = 0; nt < 8; ++nt) {
      bf8_t b = *(const bf8_t*)(wbuf + (nt * 16 + l15) * D + kc * 32 + quad * 8);
      acc[nt] = MF(afr[kc], b, acc[nt]);
    }
}

// ---------------- weight prep: fp32 W[k][n] -> bf16 WT[n][k], 9 matrices ----------------
__global__ __launch_bounds__(256) void prep_weights(
    const float* __restrict__ Wq, const float* __restrict__ Wk,
    const float* __restrict__ Wr, const float* __restrict__ Wro,
    unsigned short* __restrict__ WT) {
  const int m = blockIdx.y;
  const float* src;
  if (m < 2) src = Wq + m * D * D;
  else if (m < 4) src = Wk + (m - 2) * D * D;
  else if (m < 6) src = Wr + (m - 4) * D * D;
  else src = Wro + (m - 6) * D * D;
  unsigned short* dstp = WT + m * D * D;
  const int t = threadIdx.x;
  const int n = blockIdx.x * 2 + (t >> 7);
  const int k = t & 127;
  dstp[n * D + k] = f2bf(src[k * D + n]);
}

__global__ __launch_bounds__(256) void convert_feats(const float* __restrict__ in,
                                                     unsigned short* __restrict__ out) {
  int i = (blockIdx.x * 256 + threadIdx.x) * 4;
  float4 v = *(const float4*)(in + i);
  ushort4 o = {f2bf(v.x), f2bf(v.y), f2bf(v.z), f2bf(v.w)};
  *(ushort4*)(out + i) = o;
}

// ---------------- CSR build: MSD counting sort, zero global atomics ----------------
__global__ __launch_bounds__(256) void p1_hist(const int* __restrict__ dst,
                                               int* __restrict__ H) {
  __shared__ int cnt[NB2];
  const int t = threadIdx.x;
  const int blk = blockIdx.x;
  if (t < NB2) cnt[t] = 0;
  __syncthreads();
  const int beg = blk * TILE1, end = beg + TILE1;
  for (int i = beg + t; i < end; i += 256) atomicAdd(&cnt[dst[i] >> 8], 1);
  __syncthreads();
  if (t < NB2) H[t * NBLK1 + blk] = cnt[t];
}

__global__ __launch_bounds__(256) void p1_scanA(const int* __restrict__ H,
                                                int* __restrict__ binbase) {
  __shared__ int bs[NB2];
  __shared__ int sd[256];
  const int t = threadIdx.x;
  const int wave = t >> 6, lane = t & 63;
  for (int bin = wave; bin < NB2; bin += 4) {
    const int* row = H + bin * NBLK1;
    int v = row[lane] + row[lane + 64] + row[lane + 128] + row[lane + 192];
    for (int off = 32; off; off >>= 1) v += __shfl_down(v, off, 64);
    if (lane == 0) bs[bin] = v;
  }
  __syncthreads();
  int x = (t < NB2) ? bs[t] : 0;
  sd[t] = x;
  __syncthreads();
  int acc = x;
  for (int off = 1; off < 256; off <<= 1) {
    int y = (t >= off) ? sd[t - off] : 0;
    __syncthreads();
    acc += y;
    sd[t] = acc;
    __syncthreads();
  }
  if (t < NB2) binbase[t] = acc - x;
  if (t == 0) binbase[NB2] = NE;
}

__global__ __launch_bounds__(256) void p1_scanC(const int* __restrict__ H,
                                                const int* __restrict__ binbase,
                                                int* __restrict__ gofs) {
  __shared__ int sd[256];
  const int bin = blockIdx.x;
  const int t = threadIdx.x;
  int x = H[bin * NBLK1 + t];
  sd[t] = x;
  __syncthreads();
  int acc = x;
  for (int off = 1; off < 256; off <<= 1) {
    int y = (t >= off) ? sd[t - off] : 0;
    __syncthreads();
    acc += y;
    sd[t] = acc;
    __syncthreads();
  }
  gofs[bin * NBLK1 + t] = binbase[bin] + (acc - x);
}

__global__ __launch_bounds__(256) void p1_scatter(const int* __restrict__ src,
                                                  const int* __restrict__ dst,
                                                  const int* __restrict__ gofs,
                                                  unsigned int* __restrict__ ebuf) {
  __shared__ int lofs[NB2];
  const int t = threadIdx.x;
  const int blk = blockIdx.x;
  if (t < NB2) lofs[t] = gofs[t * NBLK1 + blk];
  __syncthreads();
  const int beg = blk * TILE1, end = beg + TILE1;
  for (int i = beg + t; i < end; i += 256) {
    unsigned int d = (unsigned int)dst[i];
    int pos = atomicAdd(&lofs[d >> 8], 1);
    ebuf[pos] = (unsigned int)src[i] | (d << 16);
  }
}

__global__ __launch_bounds__(256) void p2_sort(const int* __restrict__ binbase,
                                               const unsigned int* __restrict__ ebuf,
                                               int* __restrict__ ssrc,
                                               int* __restrict__ rowptr,
                                               int* __restrict__ deg) {
  __shared__ int cnt[256], fill[256], sd[256];
  __shared__ unsigned int sorted[CAP2];
  const int b = blockIdx.x;
  const int t = threadIdx.x;
  const int beg = binbase[b], end = binbase[b + 1];
  const int n = end - beg;
  cnt[t] = 0;
  __syncthreads();
  for (int i = beg + t; i < end; i += 256)
    atomicAdd(&cnt[(ebuf[i] >> 16) & 255], 1);
  __syncthreads();
  int x = cnt[t];
  sd[t] = x;
  __syncthreads();
  int acc = x;
  for (int off = 1; off < 256; off <<= 1) {
    int y = (t >= off) ? sd[t - off] : 0;
    __syncthreads();
    acc += y;
    sd[t] = acc;
    __syncthreads();
  }
  const int excl = acc - x;
  fill[t] = excl;
  __syncthreads();
  for (int i = beg + t; i < end; i += 256) {
    unsigned int p = ebuf[i];
    int pos = atomicAdd(&fill[(p >> 16) & 255], 1);
    if (pos < CAP2) sorted[pos] = p;
  }
  __syncthreads();
  for (int i = t; i < n; i += 256) ssrc[beg + i] = (int)(sorted[i] & 0xFFFFu);
  const int node = (b << 8) + t;
  if (node < NN) {
    rowptr[node] = beg + excl;
    deg[node] = x;
  }
  if (b == 0 && t == 0) rowptr[NN] = NE;
}

// ---------------- aggregation: wide-gather (16 lanes/edge, uint4) ----------------
// one node per wave; lanes: sub=lane&15 (channel group), grp=lane>>4 (edge slot)
__global__ __launch_bounds__(256) void aggregate(
    const int* __restrict__ rowptr, const int* __restrict__ ssrc,
    const int* __restrict__ deg,
    const unsigned short* __restrict__ hq, const unsigned short* __restrict__ hk,
    unsigned short* __restrict__ ag) {
  const int wave = threadIdx.x >> 6, lane = threadIdx.x & 63;
  const int v = blockIdx.x * 4 + wave;
  if (v >= NN) return;
  const int sub = lane & 15, grp = lane >> 4;
  const int beg = rowptr[v], end = rowptr[v + 1];

  uint4 qb = *(const uint4*)(hq + (size_t)v * D + sub * 8);
  float q[8];
  q[0] = bf2f(qb.x & 0xFFFFu); q[1] = bf2f(qb.x >> 16);
  q[2] = bf2f(qb.y & 0xFFFFu); q[3] = bf2f(qb.y >> 16);
  q[4] = bf2f(qb.z & 0xFFFFu); q[5] = bf2f(qb.z >> 16);
  q[6] = bf2f(qb.w & 0xFFFFu); q[7] = bf2f(qb.w >> 16);

  float a[8] = {0.f, 0.f, 0.f, 0.f, 0.f, 0.f, 0.f, 0.f};
  int e = beg + grp;
  int s = (e < end) ? ssrc[e] : -1;
  while (s >= 0) {
    const uint4 kb = *(const uint4*)(hk + (size_t)s * D + sub * 8);
    e += 4;
    s = (e < end) ? ssrc[e] : -1;   // prefetch next index while kb is in flight
    float m;
    m = q[0] + bf2f(kb.x & 0xFFFFu); a[0] += m >= 0.f ? m : NEG * m;
    m = q[1] + bf2f(kb.x >> 16);     a[1] += m >= 0.f ? m : NEG * m;
    m = q[2] + bf2f(kb.y & 0xFFFFu); a[2] += m >= 0.f ? m : NEG * m;
    m = q[3] + bf2f(kb.y >> 16);     a[3] += m >= 0.f ? m : NEG * m;
    m = q[4] + bf2f(kb.z & 0xFFFFu); a[4] += m >= 0.f ? m : NEG * m;
    m = q[5] + bf2f(kb.z >> 16);     a[5] += m >= 0.f ? m : NEG * m;
    m = q[6] + bf2f(kb.w & 0xFFFFu); a[6] += m >= 0.f ? m : NEG * m;
    m = q[7] + bf2f(kb.w >> 16);     a[7] += m >= 0.f ? m : NEG * m;
  }
  // reduce the 4 edge-slot groups (lanes sub, sub+16, sub+32, sub+48)
#pragma unroll
  for (int j = 0; j < 8; ++j) {
    a[j] += __shfl_xor(a[j], 16, 64);
    a[j] += __shfl_xor(a[j], 32, 64);
  }
  if (grp == 0) {
    float inv = 1.f / fmaxf((float)deg[v], 1.f);
    uint4 o;
    o.x = (unsigned int)f2bf(a[0] * inv) | ((unsigned int)f2bf(a[1] * inv) << 16);
    o.y = (unsigned int)f2bf(a[2] * inv) | ((unsigned int)f2bf(a[3] * inv) << 16);
    o.z = (unsigned int)f2bf(a[4] * inv) | ((unsigned int)f2bf(a[5] * inv) << 16);
    o.w = (unsigned int)f2bf(a[6] * inv) | ((unsigned int)f2bf(a[7] * inv) << 16);
    *(uint4*)(ag + (size_t)v * D + sub * 8) = o;
  }
}

// ---------------- single-phase GEMM, 64-row tiles, weight selected by blockIdx.x ------
template <bool LEAKY>
__global__ __launch_bounds__(256) void gemm64(const unsigned short* __restrict__ A,
                                              const unsigned short* __restrict__ WT0,
                                              const float* __restrict__ b0,
                                              unsigned short* __restrict__ C0,
                                              const unsigned short* __restrict__ WT1,
                                              const float* __restrict__ b1,
                                              unsigned short* __restrict__ C1) {
  __shared__ unsigned short wbuf[D * D];
  const int t = threadIdx.x, wave = t >> 6, lane = t & 63;
  const int l15 = lane & 15, quad = lane >> 4;
  const int sel = blockIdx.x;
  const unsigned short* WT = sel ? WT1 : WT0;
  const float* bias = sel ? b1 : b0;
  unsigned short* C = sel ? C1 : C0;
  const int base = blockIdx.y * 64 + wave * 16;

  stage_w(wbuf, WT, t);
  bf8_t afr[4];
  load_a16(A, base, l15, quad, afr);
  __syncthreads();

  f4_t acc[8] = {};
  tile16(wbuf, afr, l15, quad, acc);

#pragma unroll
  for (int nt = 0; nt < 8; ++nt) {
    int col = nt * 16 + l15;
    float b = bias[col];
#pragma unroll
    for (int reg = 0; reg < 4; ++reg) {
      int row = base + quad * 4 + reg;
      if (row < NN) {
        float v = acc[nt][reg] + b;
        if (LEAKY) v = v >= 0.f ? v : NEG * v;
        C[(size_t)row * D + col] = f2bf(v);
      }
    }
  }
}

// ---------------- JK readout: out = x0@Wro0 + h1@Wro1 + h2@Wro2 + sum(b) -------------
__global__ __launch_bounds__(256) void readout(const unsigned short* __restrict__ x0,
                                               const unsigned short* __restrict__ h1,
                                               const unsigned short* __restrict__ h2,
                                               const unsigned short* __restrict__ WTro,
                                               const float* __restrict__ bro_,
                                               float* __restrict__ out) {
  __shared__ unsigned short wbuf[D * D];
  const int t = threadIdx.x, wave = t >> 6, lane = t & 63;
  const int l15 = lane & 15, quad = lane >> 4;
  const int base = blockIdx.x * 64 + wave * 16;
  const unsigned short* As[3] = {x0, h1, h2};

  f4_t acc[8] = {};
#pragma unroll
  for (int ph = 0; ph < 3; ++ph) {
    stage_w(wbuf, WTro + (size_t)ph * D * D, t);
    bf8_t afr[4];
    load_a16(As[ph], base, l15, quad, afr);
    __syncthreads();
    tile16(wbuf, afr, l15, quad, acc);
    if (ph < 2) __syncthreads();  // wbuf reads done before restage
  }

#pragma unroll
  for (int nt = 0; nt < 8; ++nt) {
    int col = nt * 16 + l15;
    float b = bro_[col] + bro_[D + col] + bro_[2 * D + col];
#pragma unroll
    for (int reg = 0; reg < 4; ++reg) {
      int row = base + quad * 4 + reg;
      if (row < NN) out[(size_t)row * D + col] = acc[nt][reg] + b;
    }
  }
}

// ---------------- launch ----------------
extern "C" void kernel_launch(void* const* d_in, const int* in_sizes, int n_in,
                              void* d_out, int out_size, void* d_ws, size_t ws_size,
                              hipStream_t stream) {
  const float* feats = (const float*)d_in[0];
  const float* Wq = (const float*)d_in[1];
  const float* bq = (const float*)d_in[2];
  const float* Wk = (const float*)d_in[3];
  const float* bk = (const float*)d_in[4];
  const float* Wr = (const float*)d_in[5];
  const float* br = (const float*)d_in[6];
  const float* Wro = (const float*)d_in[7];
  const float* bro = (const float*)d_in[8];
  const int* src = (const int*)d_in[9];
  const int* dst = (const int*)d_in[10];
  float* out = (float*)d_out;

  size_t off = 0;
  char* base = (char*)d_ws;
  auto alloc = [&](size_t bytes) -> void* {
    void* p = base + off;
    off += (bytes + 255) & ~(size_t)255;
    return p;
  };
  int* H = (int*)alloc((size_t)NB2 * NBLK1 * 4);
  int* gofs = (int*)alloc((size_t)NB2 * NBLK1 * 4);
  int* binbase = (int*)alloc((size_t)(NB2 + 1) * 4);
  unsigned int* ebuf = (unsigned int*)alloc((size_t)NE * 4);
  int* ssrc = (int*)alloc((size_t)NE * 4);
  int* rowptr = (int*)alloc((size_t)(NN + 1) * 4);
  int* deg = (int*)alloc((size_t)NN * 4);
  unsigned short* WT = (unsigned short*)alloc((size_t)9 * D * D * 2);
  unsigned short* x0 = (unsigned short*)alloc((size_t)NN * D * 2);
  unsigned short* hq = (unsigned short*)alloc((size_t)NN * D * 2);
  unsigned short* hk = (unsigned short*)alloc((size_t)NN * D * 2);
  unsigned short* ag = (unsigned short*)alloc((size_t)NN * D * 2);
  unsigned short* h1 = (unsigned short*)alloc((size_t)NN * D * 2);
  unsigned short* h2 = (unsigned short*)alloc((size_t)NN * D * 2);

  prep_weights<<<dim3(64, 9), 256, 0, stream>>>(Wq, Wk, Wr, Wro, WT);
  convert_feats<<<6250, 256, 0, stream>>>(feats, x0);

  p1_hist<<<NBLK1, 256, 0, stream>>>(dst, H);
  p1_scanA<<<1, 256, 0, stream>>>(H, binbase);
  p1_scanC<<<NB2, 256, 0, stream>>>(H, binbase, gofs);
  p1_scatter<<<NBLK1, 256, 0, stream>>>(src, dst, gofs, ebuf);
  p2_sort<<<NB2, 256, 0, stream>>>(binbase, ebuf, ssrc, rowptr, deg);

  const size_t WM = (size_t)D * D;
  const int ab = (NN + 3) / 4;

  // ---- layer 0 ----
  gemm64<false><<<dim3(2, NT64), 256, 0, stream>>>(x0, WT + 0 * WM, bq, hq,
                                                   WT + 2 * WM, bk, hk);
  aggregate<<<ab, 256, 0, stream>>>(rowptr, ssrc, deg, hq, hk, ag);
  gemm64<true><<<dim3(1, NT64), 256, 0, stream>>>(ag, WT + 4 * WM, br, h1,
                                                  WT + 4 * WM, br, h1);
  // ---- layer 1 ----
  gemm64<false><<<dim3(2, NT64), 256, 0, stream>>>(h1, WT + 1 * WM, bq + D, hq,
                                                   WT + 3 * WM, bk + D, hk);
  aggregate<<<ab, 256, 0, stream>>>(rowptr, ssrc, deg, hq, hk, ag);
  gemm64<true><<<dim3(1, NT64), 256, 0, stream>>>(ag, WT + 5 * WM, br + D, h2,
                                                  WT + 5 * WM, br + D, h2);
  // ---- JK readout ----
  readout<<<NT64, 256, 0, stream>>>(x0, h1, h2, WT + 6 * WM, bro, out);
}

// Round 7
// 317.421 us; speedup vs baseline: 1.4588x; 1.0221x over previous
//
#include <hip/hip_runtime.h>

#define NN 50000
#define NE 800000
#define D 128
#define NEG 0.2f

#define NBLK1 256        // pass-1 blocks
#define TILE1 3125       // NE / NBLK1 (exact)
#define NB2 196          // coarse buckets (dst>>8)
#define CAP2 8192        // max edges per coarse bucket
#define NT64 782         // ceil(NN/64) row tiles

// setup kernel block ranges
#define SB_PREP 576              // 9 matrices x 64 blocks
#define SB_CONV 6250             // NN*D/4/256
#define SB_HIST NBLK1
#define SB_TOTAL (SB_PREP + SB_CONV + SB_HIST)

typedef short bf8_t __attribute__((ext_vector_type(8)));   // 8 x bf16 (16 B)
typedef float f4_t __attribute__((ext_vector_type(4)));

__device__ __forceinline__ unsigned short f2bf(float f) {
  unsigned int u = __float_as_uint(f);
  return (unsigned short)((u + 0x7FFF + ((u >> 16) & 1)) >> 16);  // RNE
}
__device__ __forceinline__ float bf2f(unsigned int b) { return __uint_as_float(b << 16); }

__device__ __forceinline__ f4_t MF(bf8_t a, bf8_t b, f4_t c) {
  return __builtin_amdgcn_mfma_f32_16x16x32_bf16(a, b, c, 0, 0, 0);
}

// ---------------- GEMM building blocks (64-row tile, 4 waves, 16 rows/wave) ----------

__device__ __forceinline__ void stage_w(unsigned short* wbuf,
                                        const unsigned short* __restrict__ WT, int t) {
#pragma unroll
  for (int i = 0; i < 8; ++i) {
    int idx8 = t + i * 256;
    *(uint4*)(wbuf + idx8 * 8) = *(const uint4*)(WT + idx8 * 8);
  }
}

__device__ __forceinline__ void load_a16(const unsigned short* __restrict__ A,
                                         int base, int l15, int quad, bf8_t (&afr)[4]) {
  int r = base + l15;
  if (r >= NN) r = NN - 1;
  const unsigned short* p = A + (size_t)r * D + quad * 8;
#pragma unroll
  for (int kc = 0; kc < 4; ++kc) afr[kc] = *(const bf8_t*)(p + kc * 32);
}

__device__ __forceinline__ void tile16(const unsigned short* wbuf, const bf8_t (&afr)[4],
                                       int l15, int quad, f4_t (&acc)[8]) {
#pragma unroll
  for (int kc = 0; kc < 4; ++kc)
#pragma unroll
    for (int nt = 0; nt < 8; ++nt) {
      bf8_t b = *(const bf8_t*)(wbuf + (nt * 16 + l15) * D + kc * 32 + quad * 8);
      acc[nt] = MF(afr[kc], b, acc[nt]);
    }
}

// ---------------- setup: weight prep + feats convert + coarse histogram --------------
__global__ __launch_bounds__(256) void setup(
    const float* __restrict__ Wq, const float* __restrict__ Wk,
    const float* __restrict__ Wr, const float* __restrict__ Wro,
    const float* __restrict__ feats, const int* __restrict__ dst,
    unsigned short* __restrict__ WT, unsigned short* __restrict__ x0,
    int* __restrict__ H) {
  __shared__ int cnt[NB2];
  const int b = blockIdx.x;
  const int t = threadIdx.x;
  if (b < SB_PREP) {
    const int m = b >> 6, xb = b & 63;
    const float* src;
    if (m < 2) src = Wq + m * D * D;
    else if (m < 4) src = Wk + (m - 2) * D * D;
    else if (m < 6) src = Wr + (m - 4) * D * D;
    else src = Wro + (m - 6) * D * D;
    const int n = xb * 2 + (t >> 7);
    const int k = t & 127;
    WT[(size_t)m * D * D + n * D + k] = f2bf(src[k * D + n]);
  } else if (b < SB_PREP + SB_CONV) {
    int i = ((b - SB_PREP) * 256 + t) * 4;
    float4 v = *(const float4*)(feats + i);
    ushort4 o = {f2bf(v.x), f2bf(v.y), f2bf(v.z), f2bf(v.w)};
    *(ushort4*)(x0 + i) = o;
  } else {
    const int blk = b - SB_PREP - SB_CONV;
    if (t < NB2) cnt[t] = 0;
    __syncthreads();
    const int beg = blk * TILE1, end = beg + TILE1;
    for (int i = beg + t; i < end; i += 256) atomicAdd(&cnt[dst[i] >> 8], 1);
    __syncthreads();
    if (t < NB2) H[t * NBLK1 + blk] = cnt[t];
  }
}

// ---------------- p1_scan: per-bin block computes its own base + row scan ------------
__global__ __launch_bounds__(256) void p1_scan(const int* __restrict__ H,
                                               int* __restrict__ gofs) {
  __shared__ int sd[256];
  __shared__ int wsum[4];
  const int bin = blockIdx.x;
  const int t = threadIdx.x;
  const int wave = t >> 6, lane = t & 63;
  // base = sum of all earlier bins' totals
  int part = 0;
  for (int b2 = 0; b2 < bin; ++b2) part += H[b2 * NBLK1 + t];
  for (int off = 32; off; off >>= 1) part += __shfl_down(part, off, 64);
  if (lane == 0) wsum[wave] = part;
  __syncthreads();
  const int base = wsum[0] + wsum[1] + wsum[2] + wsum[3];
  // exclusive scan of own row
  int x = H[bin * NBLK1 + t];
  sd[t] = x;
  __syncthreads();
  int acc = x;
  for (int off = 1; off < 256; off <<= 1) {
    int y = (t >= off) ? sd[t - off] : 0;
    __syncthreads();
    acc += y;
    sd[t] = acc;
    __syncthreads();
  }
  gofs[bin * NBLK1 + t] = base + (acc - x);
}

__global__ __launch_bounds__(256) void p1_scatter(const int* __restrict__ src,
                                                  const int* __restrict__ dst,
                                                  const int* __restrict__ gofs,
                                                  unsigned int* __restrict__ ebuf) {
  __shared__ int lofs[NB2];
  const int t = threadIdx.x;
  const int blk = blockIdx.x;
  if (t < NB2) lofs[t] = gofs[t * NBLK1 + blk];
  __syncthreads();
  const int beg = blk * TILE1, end = beg + TILE1;
  for (int i = beg + t; i < end; i += 256) {
    unsigned int d = (unsigned int)dst[i];
    int pos = atomicAdd(&lofs[d >> 8], 1);
    ebuf[pos] = (unsigned int)src[i] | (d << 16);
  }
}

// ---------------- merged: p2 counting sort (196 blocks) + layer-0 QK GEMM ------------
__global__ __launch_bounds__(256) void sort_qk0(
    const int* __restrict__ gofs, const unsigned int* __restrict__ ebuf,
    int* __restrict__ ssrc, int* __restrict__ rowptr, int* __restrict__ deg,
    const unsigned short* __restrict__ x0,
    const unsigned short* __restrict__ WTq, const float* __restrict__ bq_,
    const unsigned short* __restrict__ WTk, const float* __restrict__ bk_,
    unsigned short* __restrict__ hq, unsigned short* __restrict__ hk) {
  __shared__ __align__(16) unsigned char smraw[35840];  // max(sort 35KB, wbuf 32KB)
  const int t = threadIdx.x;
  const int gx = blockIdx.x;
  if (gx < NB2) {
    int* cnt = (int*)smraw;
    int* fill = cnt + 256;
    int* sd = fill + 256;
    unsigned int* sorted = (unsigned int*)(sd + 256);
    const int b = gx;
    const int beg = gofs[b * NBLK1];
    const int end = (b + 1 < NB2) ? gofs[(b + 1) * NBLK1] : NE;
    const int n = end - beg;
    cnt[t] = 0;
    __syncthreads();
    for (int i = beg + t; i < end; i += 256)
      atomicAdd(&cnt[(ebuf[i] >> 16) & 255], 1);
    __syncthreads();
    int x = cnt[t];
    sd[t] = x;
    __syncthreads();
    int acc = x;
    for (int off = 1; off < 256; off <<= 1) {
      int y = (t >= off) ? sd[t - off] : 0;
      __syncthreads();
      acc += y;
      sd[t] = acc;
      __syncthreads();
    }
    const int excl = acc - x;
    fill[t] = excl;
    __syncthreads();
    for (int i = beg + t; i < end; i += 256) {
      unsigned int p = ebuf[i];
      int pos = atomicAdd(&fill[(p >> 16) & 255], 1);
      if (pos < CAP2) sorted[pos] = p;
    }
    __syncthreads();
    for (int i = t; i < n; i += 256) ssrc[beg + i] = (int)(sorted[i] & 0xFFFFu);
    const int node = (b << 8) + t;
    if (node < NN) {
      rowptr[node] = beg + excl;
      deg[node] = x;
    }
    if (b == 0 && t == 0) rowptr[NN] = NE;
  } else {
    unsigned short* wbuf = (unsigned short*)smraw;
    const int g = gx - NB2;
    const int sel = g & 1, tile = g >> 1;
    const int wave = t >> 6, lane = t & 63;
    const int l15 = lane & 15, quad = lane >> 4;
    const int base = tile * 64 + wave * 16;
    stage_w(wbuf, sel ? WTk : WTq, t);
    bf8_t afr[4];
    load_a16(x0, base, l15, quad, afr);
    __syncthreads();
    f4_t acc[8] = {};
    tile16(wbuf, afr, l15, quad, acc);
    const float* bias = sel ? bk_ : bq_;
    unsigned short* C = sel ? hk : hq;
#pragma unroll
    for (int nt = 0; nt < 8; ++nt) {
      int col = nt * 16 + l15;
      float bb = bias[col];
#pragma unroll
      for (int reg = 0; reg < 4; ++reg) {
        int row = base + quad * 4 + reg;
        if (row < NN) C[(size_t)row * D + col] = f2bf(acc[nt][reg] + bb);
      }
    }
  }
}

// ---------------- aggregation: wide gather, 8 loads in flight per wave ---------------
#define PROC(kb)                                                     \
  {                                                                  \
    float m;                                                         \
    m = q[0] + bf2f(kb.x & 0xFFFFu); a[0] += m >= 0.f ? m : NEG * m; \
    m = q[1] + bf2f(kb.x >> 16);     a[1] += m >= 0.f ? m : NEG * m; \
    m = q[2] + bf2f(kb.y & 0xFFFFu); a[2] += m >= 0.f ? m : NEG * m; \
    m = q[3] + bf2f(kb.y >> 16);     a[3] += m >= 0.f ? m : NEG * m; \
    m = q[4] + bf2f(kb.z & 0xFFFFu); a[4] += m >= 0.f ? m : NEG * m; \
    m = q[5] + bf2f(kb.z >> 16);     a[5] += m >= 0.f ? m : NEG * m; \
    m = q[6] + bf2f(kb.w & 0xFFFFu); a[6] += m >= 0.f ? m : NEG * m; \
    m = q[7] + bf2f(kb.w >> 16);     a[7] += m >= 0.f ? m : NEG * m; \
  }

__global__ __launch_bounds__(256) void aggregate(
    const int* __restrict__ rowptr, const int* __restrict__ ssrc,
    const int* __restrict__ deg,
    const unsigned short* __restrict__ hq, const unsigned short* __restrict__ hk,
    unsigned short* __restrict__ ag) {
  const int wave = threadIdx.x >> 6, lane = threadIdx.x & 63;
  const int v = blockIdx.x * 4 + wave;
  if (v >= NN) return;
  const int sub = lane & 15, grp = lane >> 4;
  const int beg = rowptr[v], end = rowptr[v + 1];

  uint4 qb = *(const uint4*)(hq + (size_t)v * D + sub * 8);
  float q[8];
  q[0] = bf2f(qb.x & 0xFFFFu); q[1] = bf2f(qb.x >> 16);
  q[2] = bf2f(qb.y & 0xFFFFu); q[3] = bf2f(qb.y >> 16);
  q[4] = bf2f(qb.z & 0xFFFFu); q[5] = bf2f(qb.z >> 16);
  q[6] = bf2f(qb.w & 0xFFFFu); q[7] = bf2f(qb.w >> 16);

  float a[8] = {0.f, 0.f, 0.f, 0.f, 0.f, 0.f, 0.f, 0.f};
  int e = beg + grp;
  for (; e + 4 < end; e += 8) {   // two edge streams -> 8 x 16B in flight per wave
    int s0 = ssrc[e];
    int s1 = ssrc[e + 4];
    uint4 k0 = *(const uint4*)(hk + (size_t)s0 * D + sub * 8);
    uint4 k1 = *(const uint4*)(hk + (size_t)s1 * D + sub * 8);
    PROC(k0);
    PROC(k1);
  }
  if (e < end) {
    int s0 = ssrc[e];
    uint4 k0 = *(const uint4*)(hk + (size_t)s0 * D + sub * 8);
    PROC(k0);
  }
#pragma unroll
  for (int j = 0; j < 8; ++j) {
    a[j] += __shfl_xor(a[j], 16, 64);
    a[j] += __shfl_xor(a[j], 32, 64);
  }
  if (grp == 0) {
    float inv = 1.f / fmaxf((float)deg[v], 1.f);
    uint4 o;
    o.x = (unsigned int)f2bf(a[0] * inv) | ((unsigned int)f2bf(a[1] * inv) << 16);
    o.y = (unsigned int)f2bf(a[2] * inv) | ((unsigned int)f2bf(a[3] * inv) << 16);
    o.z = (unsigned int)f2bf(a[4] * inv) | ((unsigned int)f2bf(a[5] * inv) << 16);
    o.w = (unsigned int)f2bf(a[6] * inv) | ((unsigned int)f2bf(a[7] * inv) << 16);
    *(uint4*)(ag + (size_t)v * D + sub * 8) = o;
  }
}

// ---------------- single-phase GEMM, 64-row tiles, dual weight via blockIdx.x --------
template <bool LEAKY>
__global__ __launch_bounds__(256) void gemm64(const unsigned short* __restrict__ A,
                                              const unsigned short* __restrict__ WT0,
                                              const float* __restrict__ b0,
                                              unsigned short* __restrict__ C0,
                                              const unsigned short* __restrict__ WT1,
                                              const float* __restrict__ b1,
                                              unsigned short* __restrict__ C1) {
  __shared__ unsigned short wbuf[D * D];
  const int t = threadIdx.x, wave = t >> 6, lane = t & 63;
  const int l15 = lane & 15, quad = lane >> 4;
  const int sel = blockIdx.x;
  const unsigned short* WT = sel ? WT1 : WT0;
  const float* bias = sel ? b1 : b0;
  unsigned short* C = sel ? C1 : C0;
  const int base = blockIdx.y * 64 + wave * 16;

  stage_w(wbuf, WT, t);
  bf8_t afr[4];
  load_a16(A, base, l15, quad, afr);
  __syncthreads();

  f4_t acc[8] = {};
  tile16(wbuf, afr, l15, quad, acc);

#pragma unroll
  for (int nt = 0; nt < 8; ++nt) {
    int col = nt * 16 + l15;
    float b = bias[col];
#pragma unroll
    for (int reg = 0; reg < 4; ++reg) {
      int row = base + quad * 4 + reg;
      if (row < NN) {
        float v = acc[nt][reg] + b;
        if (LEAKY) v = v >= 0.f ? v : NEG * v;
        C[(size_t)row * D + col] = f2bf(v);
      }
    }
  }
}

// ---------------- JK readout: out = x0@Wro0 + h1@Wro1 + h2@Wro2 + sum(b) -------------
__global__ __launch_bounds__(256) void readout(const unsigned short* __restrict__ x0,
                                               const unsigned short* __restrict__ h1,
                                               const unsigned short* __restrict__ h2,
                                               const unsigned short* __restrict__ WTro,
                                               const float* __restrict__ bro_,
                                               float* __restrict__ out) {
  __shared__ unsigned short wbuf[D * D];
  const int t = threadIdx.x, wave = t >> 6, lane = t & 63;
  const int l15 = lane & 15, quad = lane >> 4;
  const int base = blockIdx.x * 64 + wave * 16;
  const unsigned short* As[3] = {x0, h1, h2};

  f4_t acc[8] = {};
#pragma unroll
  for (int ph = 0; ph < 3; ++ph) {
    stage_w(wbuf, WTro + (size_t)ph * D * D, t);
    bf8_t afr[4];
    load_a16(As[ph], base, l15, quad, afr);
    __syncthreads();
    tile16(wbuf, afr, l15, quad, acc);
    if (ph < 2) __syncthreads();
  }

#pragma unroll
  for (int nt = 0; nt < 8; ++nt) {
    int col = nt * 16 + l15;
    float b = bro_[col] + bro_[D + col] + bro_[2 * D + col];
#pragma unroll
    for (int reg = 0; reg < 4; ++reg) {
      int row = base + quad * 4 + reg;
      if (row < NN) out[(size_t)row * D + col] = acc[nt][reg] + b;
    }
  }
}

// ---------------- launch ----------------
extern "C" void kernel_launch(void* const* d_in, const int* in_sizes, int n_in,
                              void* d_out, int out_size, void* d_ws, size_t ws_size,
                              hipStream_t stream) {
  const float* feats = (const float*)d_in[0];
  const float* Wq = (const float*)d_in[1];
  const float* bq = (const float*)d_in[2];
  const float* Wk = (const float*)d_in[3];
  const float* bk = (const float*)d_in[4];
  const float* Wr = (const float*)d_in[5];
  const float* br = (const float*)d_in[6];
  const float* Wro = (const float*)d_in[7];
  const float* bro = (const float*)d_in[8];
  const int* src = (const int*)d_in[9];
  const int* dst = (const int*)d_in[10];
  float* out = (float*)d_out;

  size_t off = 0;
  char* base = (char*)d_ws;
  auto alloc = [&](size_t bytes) -> void* {
    void* p = base + off;
    off += (bytes + 255) & ~(size_t)255;
    return p;
  };
  int* H = (int*)alloc((size_t)NB2 * NBLK1 * 4);
  int* gofs = (int*)alloc((size_t)NB2 * NBLK1 * 4);
  unsigned int* ebuf = (unsigned int*)alloc((size_t)NE * 4);
  int* ssrc = (int*)alloc((size_t)NE * 4);
  int* rowptr = (int*)alloc((size_t)(NN + 1) * 4);
  int* deg = (int*)alloc((size_t)NN * 4);
  unsigned short* WT = (unsigned short*)alloc((size_t)9 * D * D * 2);
  unsigned short* x0 = (unsigned short*)alloc((size_t)NN * D * 2);
  unsigned short* hq = (unsigned short*)alloc((size_t)NN * D * 2);
  unsigned short* hk = (unsigned short*)alloc((size_t)NN * D * 2);
  unsigned short* ag = (unsigned short*)alloc((size_t)NN * D * 2);
  unsigned short* h1 = (unsigned short*)alloc((size_t)NN * D * 2);
  unsigned short* h2 = (unsigned short*)alloc((size_t)NN * D * 2);

  const size_t WM = (size_t)D * D;
  const int ab = (NN + 3) / 4;

  // 1: weights + feats-convert + coarse hist (independent, one dispatch)
  setup<<<SB_TOTAL, 256, 0, stream>>>(Wq, Wk, Wr, Wro, feats, dst, WT, x0, H);
  // 2: hierarchical offsets
  p1_scan<<<NB2, 256, 0, stream>>>(H, gofs);
  // 3: bucket scatter
  p1_scatter<<<NBLK1, 256, 0, stream>>>(src, dst, gofs, ebuf);
  // 4: per-bucket sort (196 blocks) overlapped with layer-0 QK GEMM (3128 blocks)
  sort_qk0<<<NB2 + 2 * NT64, 256, 0, stream>>>(gofs, ebuf, ssrc, rowptr, deg,
                                               x0, WT + 0 * WM, bq, WT + 2 * WM, bk,
                                               hq, hk);
  // 5-6: layer 0 aggregate + Wr
  aggregate<<<ab, 256, 0, stream>>>(rowptr, ssrc, deg, hq, hk, ag);
  gemm64<true><<<dim3(1, NT64), 256, 0, stream>>>(ag, WT + 4 * WM, br, h1,
                                                  WT + 4 * WM, br, h1);
  // 7-9: layer 1
  gemm64<false><<<dim3(2, NT64), 256, 0, stream>>>(h1, WT + 1 * WM, bq + D, hq,
                                                   WT + 3 * WM, bk + D, hk);
  aggregate<<<ab, 256, 0, stream>>>(rowptr, ssrc, deg, hq, hk, ag);
  gemm64<true><<<dim3(1, NT64), 256, 0, stream>>>(ag, WT + 5 * WM, br + D, h2,
                                                  WT + 5 * WM, br + D, h2);
  // 10: JK readout
  readout<<<NT64, 256, 0, stream>>>(x0, h1, h2, WT + 6 * WM, bro, out);
}